// Round 14
// baseline (402.230 us; speedup 1.0000x reference)
//
#include <hip/hip_runtime.h>

// BootstrapEnsemble: M=100 MLPs (16 -> 128 -> 4x(128x128) -> {mu, log sigma}),
// shared batch N=16384.
//  1) cvt_weights: fp32->bf16 one-shot. Wh stored COLUMN-BLOCKED per layer
//     ([ksb 0..15][row 0..127] 16B blocks): conflict-free contiguous
//     ds_read_b128 with one base + immediate offsets.
//  2) ens_mlp: register-resident-h MLP (512 thr, LB(512,2), 8 waves,
//     wave-private 64-row n-band, ALL 128 k_out per wave, ONE barrier).
//     R14: NT-SPLIT SOFTWARE PIPELINE. Per hidden layer:
//       Phase A: MFMA acc0 = W x hf0 (ks 0..7)  INTERLEAVED with
//                build hf1 <- relu/cvt/permlane of old acc1;
//       Phase B: MFMA acc1 = W x hf1            INTERLEAVED with
//                build hf0' <- from the acc0 Phase A just wrote.
//     The builds are register-dependence-free against the co-phase MFMAs,
//     giving each wave's stream MFMA+VALU role diversity so the SIMD can
//     feed the matrix pipe from one wave while the other issues VALU
//     (pipes measured fully serialized at R12/R13: 37+38+26 ~= 101%).
//     Cost: W fragments re-read in phase B (LDS conflicts are 0; reads are
//     dependence-free and hide under MFMA).

typedef float  f32x4  __attribute__((ext_vector_type(4)));
typedef float  f32x16 __attribute__((ext_vector_type(16)));
typedef __bf16 bf16x4 __attribute__((ext_vector_type(4)));
typedef __bf16 bf16x8 __attribute__((ext_vector_type(8)));
typedef short  s16x4  __attribute__((ext_vector_type(4)));

union BF4 { bf16x4 v; uint2 u2; };

#define MODELS 100
#define NPT    16384
#define HDIM   128
#define SG_OFF (MODELS * NPT)

// d_ws layout (bf16 element offsets)
#define XB_OFF   0                       // x:    16384 x 16 (linear)
#define W1B_OFF  262144                  // W1:   100 x 128 x 16 (linear)
#define WHB_OFF  466944                  // Wh:   100 x 4 x [16 ksb][128 r][8] (col-blocked)
#define WMU_OFF  7020544                 // Wmu:  100 x 128 (linear)
#define WSG_OFF  7033344                 // Wsig: 100 x 128 (linear)

#define GTOT 880768                      // total 8-elem groups

__global__ __launch_bounds__(256) void cvt_weights(
    const float* __restrict__ x,   const float* __restrict__ W1,
    const float* __restrict__ Wh,  const float* __restrict__ Wmu,
    const float* __restrict__ Wsg, unsigned short* __restrict__ ws)
{
  int gid = blockIdx.x * 256 + threadIdx.x;
  if (gid >= GTOT) return;
  const float* src;
  unsigned int dst;
  if (gid < 32768) {
    src = x + gid * 8;                       dst = XB_OFF + gid * 8;
  } else if (gid < 58368) {
    int g = gid - 32768;
    src = W1 + g * 8;                        dst = W1B_OFF + g * 8;
  } else if (gid < 877568) {
    int g = gid - 58368;
    int chunk  = g >> 11;                    // m*4 + layer
    int within = g & 2047;
    int r   = within >> 4;                   // k_out row
    int j   = within & 15;                   // 16-byte column block
    src = Wh + (size_t)g * 8;
    dst = WHB_OFF + chunk * 16384 + (j * 128 + r) * 8;   // col-blocked
  } else if (gid < 879168) {
    int g = gid - 877568;
    src = Wmu + g * 8;                       dst = WMU_OFF + g * 8;
  } else {
    int g = gid - 879168;
    src = Wsg + g * 8;                       dst = WSG_OFF + g * 8;
  }
  f32x4 a = *(const f32x4*)src;
  f32x4 b = *(const f32x4*)(src + 4);
  BF4 lo, hi;
  lo.v = __builtin_convertvector(a, bf16x4);
  hi.v = __builtin_convertvector(b, bf16x4);
  uint4 u; u.x = lo.u2.x; u.y = lo.u2.y; u.z = hi.u2.x; u.w = hi.u2.y;
  *(uint4*)&ws[dst] = u;
}

__device__ __forceinline__ void gload_lds16(const void* g, void* l) {
  __builtin_amdgcn_global_load_lds(
      (const __attribute__((address_space(1))) void*)g,
      (__attribute__((address_space(3))) void*)l, 16, 0, 0);
}

#define MFMA32(A,B,C) __builtin_amdgcn_mfma_f32_32x32x16_bf16((A),(B),(C),0,0,0)

// One kt2 chunk of the D->B-frag rebuild: relu(bf16-packed) + permlane swap.
// Reads one f32x16 acc tile, writes hf[base] and hf[base+1].
__device__ __forceinline__ void build_chunk(const f32x16& a, bf16x8 (&hf)[8],
                                            int base) {
  const s16x4 z4 = {0, 0, 0, 0};
  uint2 P[4];
  #pragma unroll
  for (int q = 0; q < 4; ++q) {
    f32x4 v;
    v[0] = a[4*q+0]; v[1] = a[4*q+1]; v[2] = a[4*q+2]; v[3] = a[4*q+3];
    bf16x4 b = __builtin_convertvector(v, bf16x4);
    s16x4 s = __builtin_bit_cast(s16x4, b);
    s = __builtin_elementwise_max(s, z4);          // packed relu
    P[q] = __builtin_bit_cast(uint2, s);
  }
  #pragma unroll
  for (int sb = 0; sb < 2; ++sb) {
    unsigned int x0 = P[2*sb].x, y0 = P[2*sb+1].x;
    unsigned int x1 = P[2*sb].y, y1 = P[2*sb+1].y;
    asm("v_permlane32_swap_b32 %0, %1" : "+v"(x0), "+v"(y0));
    asm("v_permlane32_swap_b32 %0, %1" : "+v"(x1), "+v"(y1));
    uint4 f; f.x = x0; f.y = x1; f.z = y0; f.w = y1;
    hf[base + sb] = __builtin_bit_cast(bf16x8, f);
  }
}

__global__ __launch_bounds__(512, 2) void ens_mlp(
    const unsigned short* __restrict__ ws,
    const float* __restrict__ b1,  const float* __restrict__ bh,
    const float* __restrict__ bmu, const float* __restrict__ bsg,
    float* __restrict__ out)
{
  __shared__ unsigned short wlds[4 * HDIM * HDIM];   // 128 KB, all hidden W

  // XCD-chunked bijective swizzle: 3200 blocks = 8 XCDs * 400
  const int bid = blockIdx.x;
  const int swz = (bid & 7) * 400 + (bid >> 3);
  const int m   = swz >> 5;            // model 0..99
  const int nb0 = (swz & 31) << 9;     // 512-row chunk base

  const int t    = threadIdx.x;
  const int lane = t & 63;
  const int wv   = t >> 6;             // wave 0..7
  const int l31  = lane & 31;
  const int hi   = lane >> 5;
  const int nbw  = nb0 + wv * 64;      // this wave's private 64-row band

  // ---- stage all hidden W (col-blocked image) into LDS, async ------------
  {
    const char* src = (const char*)(ws + WHB_OFF + m * 65536);
    char* dst = (char*)wlds;
    #pragma unroll
    for (int it = 0; it < 16; ++it) {
      int off = t * 16 + it * 8192;
      gload_lds16(src + off, dst + off);
    }
  }

  bf16x8 hf0[8], hf1[8];   // h B-frags per nt: lane holds h[n][16ks+8hi+0..7]
  f32x16 acc0[4], acc1[4]; // [kt2] per nt

  // ---- layer 1 (K=16, exact) ----------------------------------------------
  {
    const unsigned short* W1m = ws + W1B_OFF + m * (HDIM * 16);
    const unsigned short* xp  = ws + XB_OFF;
    bf16x8 w1f[4], xf0, xf1;
    #pragma unroll
    for (int kt2 = 0; kt2 < 4; ++kt2)
      w1f[kt2] = *(const bf16x8*)&W1m[(kt2 * 32 + l31) * 16 + hi * 8];
    xf0 = *(const bf16x8*)&xp[(nbw +      l31) * 16 + hi * 8];
    xf1 = *(const bf16x8*)&xp[(nbw + 32 + l31) * 16 + hi * 8];
    #pragma unroll
    for (int kt2 = 0; kt2 < 4; ++kt2) {
      union { f32x16 v; f32x4 q[4]; } C;
      #pragma unroll
      for (int q = 0; q < 4; ++q)
        C.q[q] = *(const f32x4*)(b1 + m * HDIM + kt2 * 32 + q * 8 + hi * 4);
      acc0[kt2] = MFMA32(w1f[kt2], xf0, C.v);
      acc1[kt2] = MFMA32(w1f[kt2], xf1, C.v);
    }
  }
  #pragma unroll
  for (int kt2 = 0; kt2 < 4; ++kt2)
    build_chunk(acc0[kt2], hf0, 2 * kt2);

  __syncthreads();   // staging DMA complete; ONLY barrier in the kernel

  // ---- 4 hidden layers: nt-split pipeline ---------------------------------
  #pragma unroll
  for (int i = 0; i < 4; ++i) {
    const unsigned short* wl = wlds + i * 16384 + l31 * 8 + hi * 1024;
    const float* bp = bh + m * 512 + i * HDIM;

    union { f32x16 v; f32x4 q[4]; } C[4];
    #pragma unroll
    for (int kt2 = 0; kt2 < 4; ++kt2)
      #pragma unroll
      for (int q = 0; q < 4; ++q)
        C[kt2].q[q] = *(const f32x4*)(bp + kt2 * 32 + q * 8 + hi * 4);

    // Phase A: acc0 = W x hf0, interleaved with build of hf1 from OLD acc1.
    #pragma unroll
    for (int ks = 0; ks < 8; ++ks) {
      bf16x8 wf[4];
      #pragma unroll
      for (int kt2 = 0; kt2 < 4; ++kt2)
        wf[kt2] = *(const bf16x8*)(wl + kt2 * 256 + ks * 2048);
      #pragma unroll
      for (int kt2 = 0; kt2 < 4; ++kt2)
        acc0[kt2] = MFMA32(wf[kt2], hf0[ks], ks == 0 ? C[kt2].v : acc0[kt2]);
      if (ks < 4)
        build_chunk(acc1[ks], hf1, 2 * ks);   // reads old acc1 (layer i-1)
    }

    // Phase B: acc1 = W x hf1, interleaved with build of hf0 from NEW acc0.
    #pragma unroll
    for (int ks = 0; ks < 8; ++ks) {
      bf16x8 wf[4];
      #pragma unroll
      for (int kt2 = 0; kt2 < 4; ++kt2)
        wf[kt2] = *(const bf16x8*)(wl + kt2 * 256 + ks * 2048);
      #pragma unroll
      for (int kt2 = 0; kt2 < 4; ++kt2)
        acc1[kt2] = MFMA32(wf[kt2], hf1[ks], ks == 0 ? C[kt2].v : acc1[kt2]);
      if (ks < 4)
        build_chunk(acc0[ks], hf0, 2 * ks);   // feeds layer i+1 / heads
    }
  }
  // final nt=1 frags for the heads
  #pragma unroll
  for (int kt2 = 0; kt2 < 4; ++kt2)
    build_chunk(acc1[kt2], hf1, 2 * kt2);

  // ---- heads: mu (k'=0) and log-sigma (k'=1) ------------------------------
  {
    bf16x8 hw[8];
    const unsigned short* wp = ws + (l31 == 0 ? WMU_OFF : WSG_OFF) + m * HDIM;
    #pragma unroll
    for (int ks = 0; ks < 8; ++ks) {
      if (l31 < 2) {
        hw[ks] = *(const bf16x8*)&wp[ks * 16 + hi * 8];
      } else {
        uint4 z; z.x = 0u; z.y = 0u; z.z = 0u; z.w = 0u;
        hw[ks] = __builtin_bit_cast(bf16x8, z);
      }
    }
    f32x16 C;
    #pragma unroll
    for (int j = 0; j < 16; ++j) C[j] = 0.0f;
    if (hi == 0) { C[0] = bmu[m]; C[1] = bsg[m]; }

    f32x16 a2;
    #pragma unroll
    for (int ks = 0; ks < 8; ++ks)
      a2 = MFMA32(hw[ks], hf0[ks], ks == 0 ? C : a2);
    if (hi == 0) {
      int n = nbw + l31;
      out[m * NPT + n]          = a2[0];
      out[SG_OFF + m * NPT + n] = expf(a2[1]);
    }
    #pragma unroll
    for (int ks = 0; ks < 8; ++ks)
      a2 = MFMA32(hw[ks], hf1[ks], ks == 0 ? C : a2);
    if (hi == 0) {
      int n = nbw + 32 + l31;
      out[m * NPT + n]          = a2[0];
      out[SG_OFF + m * NPT + n] = expf(a2[1]);
    }
  }
}

extern "C" void kernel_launch(void* const* d_in, const int* in_sizes, int n_in,
                              void* d_out, int out_size, void* d_ws, size_t ws_size,
                              hipStream_t stream) {
  const float* x   = (const float*)d_in[0];
  const float* W1  = (const float*)d_in[1];
  const float* b1  = (const float*)d_in[2];
  const float* Wh  = (const float*)d_in[3];
  const float* bh  = (const float*)d_in[4];
  const float* Wmu = (const float*)d_in[5];
  const float* bmu = (const float*)d_in[6];
  const float* Wsg = (const float*)d_in[7];
  const float* bsg = (const float*)d_in[8];
  unsigned short* ws = (unsigned short*)d_ws;
  (void)in_sizes; (void)n_in; (void)out_size; (void)ws_size;

  cvt_weights<<<(GTOT + 255) / 256, 256, 0, stream>>>(x, W1, Wh, Wmu, Wsg, ws);
  ens_mlp<<<3200, 512, 0, stream>>>(ws, b1, bh, bmu, bsg, (float*)d_out);
}

// Round 15
// 223.012 us; speedup vs baseline: 1.8036x; 1.8036x over previous
//
#include <hip/hip_runtime.h>

// BootstrapEnsemble: M=100 MLPs (16 -> 128 -> 4x(128x128) -> {mu, log sigma}),
// shared batch N=16384.
//  1) cvt_weights: one-shot fp32->bf16 of x/W1/Wh/Wmu/Wsig into d_ws. Wh is
//     PRE-SWIZZLED (8-elem group j of row r at col 8*(j ^ (r&15))): staged
//     linearly via global_load_lds, read back conflict-free (R12: measured 0
//     bank conflicts).
//  2) ens_mlp: register-resident-h MLP (R12 config: 512 thr, LB(512,2),
//     8 waves, wave-private 64-row n-band, ALL 128 k_out per wave, h never
//     leaves registers, ONE barrier; VGPR 112 + acc in AGPR = ~240/wave ->
//     hard 2 waves/SIMD). R15: PERSISTENT WAVE-PARITY PRIORITY
//     (odd waves s_setprio(1) for the whole kernel): the high-prio wave wins
//     issue contention and runs ahead; its SIMD partner fills the stall
//     slots -> stable anti-phase (T5 mechanism). R13's one-shot stagger
//     decayed; R14's source-level interleave spilled (acc x2 = 256 regs).
//     B-frag rebuild: cvt_pk -> packed relu (v_pk_max_i16) -> permlane32_swap.

typedef float  f32x4  __attribute__((ext_vector_type(4)));
typedef float  f32x16 __attribute__((ext_vector_type(16)));
typedef __bf16 bf16x4 __attribute__((ext_vector_type(4)));
typedef __bf16 bf16x8 __attribute__((ext_vector_type(8)));
typedef short  s16x4  __attribute__((ext_vector_type(4)));

union BF4  { bf16x4 v; uint2 u2; };
union FRAG { bf16x8 v; uint4 u4; };
union PKW  { uint2 u2; s16x4 s4; };

#define MODELS 100
#define NPT    16384
#define HDIM   128
#define SG_OFF (MODELS * NPT)

// d_ws layout (bf16 element offsets)
#define XB_OFF   0                       // x:    16384 x 16 (linear)
#define W1B_OFF  262144                  // W1:   100 x 128 x 16 (linear)
#define WHB_OFF  466944                  // Wh:   100 x 4 x 128 x 128 (SWIZZLED)
#define WMU_OFF  7020544                 // Wmu:  100 x 128 (linear)
#define WSG_OFF  7033344                 // Wsig: 100 x 128 (linear)

#define GTOT 880768                      // total 8-elem groups

__global__ __launch_bounds__(256) void cvt_weights(
    const float* __restrict__ x,   const float* __restrict__ W1,
    const float* __restrict__ Wh,  const float* __restrict__ Wmu,
    const float* __restrict__ Wsg, unsigned short* __restrict__ ws)
{
  int gid = blockIdx.x * 256 + threadIdx.x;
  if (gid >= GTOT) return;
  const float* src;
  unsigned int dst;
  if (gid < 32768) {
    src = x + gid * 8;                       dst = XB_OFF + gid * 8;
  } else if (gid < 58368) {
    int g = gid - 32768;
    src = W1 + g * 8;                        dst = W1B_OFF + g * 8;
  } else if (gid < 877568) {
    int g = gid - 58368;
    int chunk  = g >> 11;                    // m*4 + layer
    int within = g & 2047;
    int r   = within >> 4;                   // k_out row
    int col = ((within & 15) * 8) ^ ((r & 15) << 3);  // full-depth swizzle
    src = Wh + (size_t)g * 8;
    dst = WHB_OFF + chunk * 16384 + r * HDIM + col;
  } else if (gid < 879168) {
    int g = gid - 877568;
    src = Wmu + g * 8;                       dst = WMU_OFF + g * 8;
  } else {
    int g = gid - 879168;
    src = Wsg + g * 8;                       dst = WSG_OFF + g * 8;
  }
  f32x4 a = *(const f32x4*)src;
  f32x4 b = *(const f32x4*)(src + 4);
  BF4 lo, hi;
  lo.v = __builtin_convertvector(a, bf16x4);
  hi.v = __builtin_convertvector(b, bf16x4);
  uint4 u; u.x = lo.u2.x; u.y = lo.u2.y; u.z = hi.u2.x; u.w = hi.u2.y;
  *(uint4*)&ws[dst] = u;
}

__device__ __forceinline__ void gload_lds16(const void* g, void* l) {
  __builtin_amdgcn_global_load_lds(
      (const __attribute__((address_space(1))) void*)g,
      (__attribute__((address_space(3))) void*)l, 16, 0, 0);
}

#define MFMA32(A,B,C) __builtin_amdgcn_mfma_f32_32x32x16_bf16((A),(B),(C),0,0,0)

// D (f32x16, per lane: col n = l31, row k' = 32*kt2 + 8*(reg>>2) + 4*hi + (reg&3))
// -> next-layer B-frags (lane holds h[n=l31][k = 16*ks + 8*hi + 0..7]).
// cvt_pk to bf16 pairs, PACKED relu (v_pk_max_i16), then permlane32_swap.
__device__ __forceinline__ void build_hfrag(const f32x16 (&acc)[2][4],
                                            uint4 (&hf)[2][8]) {
  const s16x4 z4 = {0, 0, 0, 0};
  #pragma unroll
  for (int nt = 0; nt < 2; ++nt) {
    #pragma unroll
    for (int kt2 = 0; kt2 < 4; ++kt2) {
      uint2 P[4];
      #pragma unroll
      for (int q = 0; q < 4; ++q) {
        f32x4 v;
        v[0] = acc[nt][kt2][4*q+0]; v[1] = acc[nt][kt2][4*q+1];
        v[2] = acc[nt][kt2][4*q+2]; v[3] = acc[nt][kt2][4*q+3];
        BF4 b; b.v = __builtin_convertvector(v, bf16x4);
        PKW p; p.u2 = b.u2;
        p.s4 = __builtin_elementwise_max(p.s4, z4);   // packed relu
        P[q] = p.u2;
      }
      #pragma unroll
      for (int sb = 0; sb < 2; ++sb) {
        unsigned int x0 = P[2*sb].x, y0 = P[2*sb+1].x;
        unsigned int x1 = P[2*sb].y, y1 = P[2*sb+1].y;
        asm("v_permlane32_swap_b32 %0, %1" : "+v"(x0), "+v"(y0));
        asm("v_permlane32_swap_b32 %0, %1" : "+v"(x1), "+v"(y1));
        uint4 f; f.x = x0; f.y = x1; f.z = y0; f.w = y1;
        hf[nt][2*kt2+sb] = f;
      }
    }
  }
}

__global__ __launch_bounds__(512, 2) void ens_mlp(
    const unsigned short* __restrict__ ws,
    const float* __restrict__ b1,  const float* __restrict__ bh,
    const float* __restrict__ bmu, const float* __restrict__ bsg,
    float* __restrict__ out)
{
  __shared__ unsigned short wlds[4 * HDIM * HDIM];   // 128 KB, all hidden W

  // XCD-chunked bijective swizzle: 3200 blocks = 8 XCDs * 400
  const int bid = blockIdx.x;
  const int swz = (bid & 7) * 400 + (bid >> 3);
  const int m   = swz >> 5;            // model 0..99
  const int nb0 = (swz & 31) << 9;     // 512-row chunk base

  const int t    = threadIdx.x;
  const int lane = t & 63;
  const int wv   = t >> 6;             // wave 0..7
  const int l31  = lane & 31;
  const int hi   = lane >> 5;
  const int nbw  = nb0 + wv * 64;      // this wave's private 64-row band

  // R15: persistent wave-parity priority -> stable anti-phase between the
  // two waves sharing each SIMD (odd wave wins issue contention, runs ahead;
  // even wave fills its stall slots).
  if (wv & 1) __builtin_amdgcn_s_setprio(1);

  // ---- stage all hidden W (pre-swizzled image) into LDS, async ----------
  {
    const char* src = (const char*)(ws + WHB_OFF + m * 65536);
    char* dst = (char*)wlds;
    #pragma unroll
    for (int it = 0; it < 16; ++it) {
      int off = t * 16 + it * 8192;
      gload_lds16(src + off, dst + off);
    }
  }

  uint4  hfrag[2][8];   // h B-frags: [nt][ks], lane holds h[n][16ks+8hi+0..7]
  f32x16 acc[2][4];     // [nt][kt2]

  // ---- layer 1: K=16, exact (no padding) ---------------------------------
  {
    const unsigned short* W1m = ws + W1B_OFF + m * (HDIM * 16);
    const unsigned short* xp  = ws + XB_OFF;
    FRAG w1f[4], xf[2];
    #pragma unroll
    for (int kt2 = 0; kt2 < 4; ++kt2)
      w1f[kt2].v = *(const bf16x8*)&W1m[(kt2 * 32 + l31) * 16 + hi * 8];
    #pragma unroll
    for (int nt = 0; nt < 2; ++nt)
      xf[nt].v = *(const bf16x8*)&xp[(nbw + nt * 32 + l31) * 16 + hi * 8];
    #pragma unroll
    for (int kt2 = 0; kt2 < 4; ++kt2) {
      union { f32x16 v; f32x4 q[4]; } C;
      #pragma unroll
      for (int q = 0; q < 4; ++q)
        C.q[q] = *(const f32x4*)(b1 + m * HDIM + kt2 * 32 + q * 8 + hi * 4);
      #pragma unroll
      for (int nt = 0; nt < 2; ++nt)
        acc[nt][kt2] = MFMA32(w1f[kt2].v, xf[nt].v, C.v);
    }
  }
  build_hfrag(acc, hfrag);

  __syncthreads();   // staging DMA complete; ONLY barrier in the kernel

  // ---- 4 hidden layers: h register-resident, W from LDS ------------------
  #pragma unroll
  for (int i = 0; i < 4; ++i) {
    const char* wl = (const char*)wlds + i * 32768;
    const float* bp = bh + m * 512 + i * HDIM;

    union { f32x16 v; f32x4 q[4]; } C[4];
    #pragma unroll
    for (int kt2 = 0; kt2 < 4; ++kt2)
      #pragma unroll
      for (int q = 0; q < 4; ++q)
        C[kt2].q[q] = *(const f32x4*)(bp + kt2 * 32 + q * 8 + hi * 4);

    #pragma unroll
    for (int ks = 0; ks < 8; ++ks) {
      FRAG wf[4];
      #pragma unroll
      for (int kt2 = 0; kt2 < 4; ++kt2) {
        int off = (kt2 * 32 + l31) * 256 + ((ks * 32 + hi * 16) ^ ((l31 & 15) << 4));
        wf[kt2].u4 = *(const uint4*)(wl + off);
      }
      #pragma unroll
      for (int kt2 = 0; kt2 < 4; ++kt2)
        #pragma unroll
        for (int nt = 0; nt < 2; ++nt) {
          FRAG hv; hv.u4 = hfrag[nt][ks];
          acc[nt][kt2] = MFMA32(wf[kt2].v, hv.v,
                                ks == 0 ? C[kt2].v : acc[nt][kt2]);
        }
    }
    build_hfrag(acc, hfrag);
  }

  // ---- heads: mu (k'=0) and log-sigma (k'=1) ------------------------------
  {
    FRAG hw[8];
    const unsigned short* wp = ws + (l31 == 0 ? WMU_OFF : WSG_OFF) + m * HDIM;
    #pragma unroll
    for (int ks = 0; ks < 8; ++ks) {
      if (l31 < 2) {
        hw[ks].v = *(const bf16x8*)&wp[ks * 16 + hi * 8];
      } else {
        uint4 z; z.x = 0u; z.y = 0u; z.z = 0u; z.w = 0u;
        hw[ks].u4 = z;
      }
    }
    f32x16 C;
    #pragma unroll
    for (int j = 0; j < 16; ++j) C[j] = 0.0f;
    if (hi == 0) { C[0] = bmu[m]; C[1] = bsg[m]; }

    #pragma unroll
    for (int nt = 0; nt < 2; ++nt) {
      f32x16 a2;
      #pragma unroll
      for (int ks = 0; ks < 8; ++ks) {
        FRAG hv; hv.u4 = hfrag[nt][ks];
        a2 = MFMA32(hw[ks].v, hv.v, ks == 0 ? C : a2);
      }
      if (hi == 0) {
        int n = nbw + nt * 32 + l31;
        out[m * NPT + n]          = a2[0];
        out[SG_OFF + m * NPT + n] = expf(a2[1]);
      }
    }
  }
}

extern "C" void kernel_launch(void* const* d_in, const int* in_sizes, int n_in,
                              void* d_out, int out_size, void* d_ws, size_t ws_size,
                              hipStream_t stream) {
  const float* x   = (const float*)d_in[0];
  const float* W1  = (const float*)d_in[1];
  const float* b1  = (const float*)d_in[2];
  const float* Wh  = (const float*)d_in[3];
  const float* bh  = (const float*)d_in[4];
  const float* Wmu = (const float*)d_in[5];
  const float* bmu = (const float*)d_in[6];
  const float* Wsg = (const float*)d_in[7];
  const float* bsg = (const float*)d_in[8];
  unsigned short* ws = (unsigned short*)d_ws;
  (void)in_sizes; (void)n_in; (void)out_size; (void)ws_size;

  cvt_weights<<<(GTOT + 255) / 256, 256, 0, stream>>>(x, W1, Wh, Wmu, Wsg, ws);
  ens_mlp<<<3200, 512, 0, stream>>>(ws, b1, bh, bmu, bsg, (float*)d_out);
}

// Round 17
// 220.429 us; speedup vs baseline: 1.8248x; 1.0117x over previous
//
#include <hip/hip_runtime.h>

// BootstrapEnsemble: M=100 MLPs (16 -> 128 -> 4x(128x128) -> {mu, log sigma}),
// shared batch N=16384.
//  1) cvt_weights: one-shot fp32->bf16 of x/W1/Wh/Wmu/Wsig into d_ws. Wh is
//     PRE-SWIZZLED (8-elem group j of row r at col 8*(j ^ (r&15))): staged
//     linearly via global_load_lds, read back conflict-free (measured 0
//     bank conflicts since R12).
//  2) ens_mlp: register-resident-h MLP. Block = 4 waves x 64-row band
//     (256 thr), LDS = 64 KB (W double-buffer 2x32KB) -> 2 independent
//     blocks/CU: each SIMD's two waves come from DIFFERENT blocks (no shared
//     barrier, independent phase) -> cross-wave MFMA/VALU/LDS overlap (m114).
//     R17 fixes R16's RACE: the DMA for layer i+2 into buf[i&1] is now
//     issued AFTER the barrier that proves all waves finished reading
//     buf[i&1] (R16 issued it before the reads -> absmax 0.87).
//     DMA drain chain: issued end of iter i -> drained by the vmcnt(0)
//     implicit in the barrier at end of iter i+1 -> read at iter i+2.
//     Per-wave: h in registers; B-frag rebuild = cvt_pk -> packed relu
//     (v_pk_max_i16) -> permlane32_swap. Hidden: mfma_f32_32x32x16_bf16.

typedef float  f32x4  __attribute__((ext_vector_type(4)));
typedef float  f32x16 __attribute__((ext_vector_type(16)));
typedef __bf16 bf16x4 __attribute__((ext_vector_type(4)));
typedef __bf16 bf16x8 __attribute__((ext_vector_type(8)));
typedef short  s16x4  __attribute__((ext_vector_type(4)));

union BF4  { bf16x4 v; uint2 u2; };
union FRAG { bf16x8 v; uint4 u4; };
union PKW  { uint2 u2; s16x4 s4; };

#define MODELS 100
#define NPT    16384
#define HDIM   128
#define SG_OFF (MODELS * NPT)

// d_ws layout (bf16 element offsets)
#define XB_OFF   0                       // x:    16384 x 16 (linear)
#define W1B_OFF  262144                  // W1:   100 x 128 x 16 (linear)
#define WHB_OFF  466944                  // Wh:   100 x 4 x 128 x 128 (SWIZZLED)
#define WMU_OFF  7020544                 // Wmu:  100 x 128 (linear)
#define WSG_OFF  7033344                 // Wsig: 100 x 128 (linear)

#define GTOT 880768                      // total 8-elem groups

__global__ __launch_bounds__(256) void cvt_weights(
    const float* __restrict__ x,   const float* __restrict__ W1,
    const float* __restrict__ Wh,  const float* __restrict__ Wmu,
    const float* __restrict__ Wsg, unsigned short* __restrict__ ws)
{
  int gid = blockIdx.x * 256 + threadIdx.x;
  if (gid >= GTOT) return;
  const float* src;
  unsigned int dst;
  if (gid < 32768) {
    src = x + gid * 8;                       dst = XB_OFF + gid * 8;
  } else if (gid < 58368) {
    int g = gid - 32768;
    src = W1 + g * 8;                        dst = W1B_OFF + g * 8;
  } else if (gid < 877568) {
    int g = gid - 58368;
    int chunk  = g >> 11;                    // m*4 + layer
    int within = g & 2047;
    int r   = within >> 4;                   // k_out row
    int col = ((within & 15) * 8) ^ ((r & 15) << 3);  // full-depth swizzle
    src = Wh + (size_t)g * 8;
    dst = WHB_OFF + chunk * 16384 + r * HDIM + col;
  } else if (gid < 879168) {
    int g = gid - 877568;
    src = Wmu + g * 8;                       dst = WMU_OFF + g * 8;
  } else {
    int g = gid - 879168;
    src = Wsg + g * 8;                       dst = WSG_OFF + g * 8;
  }
  f32x4 a = *(const f32x4*)src;
  f32x4 b = *(const f32x4*)(src + 4);
  BF4 lo, hi;
  lo.v = __builtin_convertvector(a, bf16x4);
  hi.v = __builtin_convertvector(b, bf16x4);
  uint4 u; u.x = lo.u2.x; u.y = lo.u2.y; u.z = hi.u2.x; u.w = hi.u2.y;
  *(uint4*)&ws[dst] = u;
}

__device__ __forceinline__ void gload_lds16(const void* g, void* l) {
  __builtin_amdgcn_global_load_lds(
      (const __attribute__((address_space(1))) void*)g,
      (__attribute__((address_space(3))) void*)l, 16, 0, 0);
}

#define MFMA32(A,B,C) __builtin_amdgcn_mfma_f32_32x32x16_bf16((A),(B),(C),0,0,0)

// D (f32x16, per lane: col n = l31, row k' = 32*kt2 + 8*(reg>>2) + 4*hi + (reg&3))
// -> next-layer B-frags (lane holds h[n=l31][k = 16*ks + 8*hi + 0..7]).
// cvt_pk to bf16 pairs, PACKED relu (v_pk_max_i16), then permlane32_swap.
__device__ __forceinline__ void build_hfrag(const f32x16 (&acc)[2][4],
                                            uint4 (&hf)[2][8]) {
  const s16x4 z4 = {0, 0, 0, 0};
  #pragma unroll
  for (int nt = 0; nt < 2; ++nt) {
    #pragma unroll
    for (int kt2 = 0; kt2 < 4; ++kt2) {
      uint2 P[4];
      #pragma unroll
      for (int q = 0; q < 4; ++q) {
        f32x4 v;
        v[0] = acc[nt][kt2][4*q+0]; v[1] = acc[nt][kt2][4*q+1];
        v[2] = acc[nt][kt2][4*q+2]; v[3] = acc[nt][kt2][4*q+3];
        BF4 b; b.v = __builtin_convertvector(v, bf16x4);
        PKW p; p.u2 = b.u2;
        p.s4 = __builtin_elementwise_max(p.s4, z4);   // packed relu
        P[q] = p.u2;
      }
      #pragma unroll
      for (int sb = 0; sb < 2; ++sb) {
        unsigned int x0 = P[2*sb].x, y0 = P[2*sb+1].x;
        unsigned int x1 = P[2*sb].y, y1 = P[2*sb+1].y;
        asm("v_permlane32_swap_b32 %0, %1" : "+v"(x0), "+v"(y0));
        asm("v_permlane32_swap_b32 %0, %1" : "+v"(x1), "+v"(y1));
        uint4 f; f.x = x0; f.y = x1; f.z = y0; f.w = y1;
        hf[nt][2*kt2+sb] = f;
      }
    }
  }
}

__global__ __launch_bounds__(256, 2) void ens_mlp(
    const unsigned short* __restrict__ ws,
    const float* __restrict__ b1,  const float* __restrict__ bh,
    const float* __restrict__ bmu, const float* __restrict__ bsg,
    float* __restrict__ out)
{
  __shared__ unsigned short wlds[2][HDIM * HDIM];   // 64 KB: W double-buffer

  // XCD-chunked bijective swizzle: 6400 blocks = 8 XCDs * 800
  const int bid = blockIdx.x;
  const int swz = (bid & 7) * 800 + (bid >> 3);
  const int m   = swz >> 6;            // model 0..99
  const int nb0 = (swz & 63) << 8;     // 256-row chunk base

  const int t    = threadIdx.x;
  const int lane = t & 63;
  const int wv   = t >> 6;             // wave 0..3
  const int l31  = lane & 31;
  const int hi   = lane >> 5;
  const int nbw  = nb0 + wv * 64;      // this wave's private 64-row band

  const unsigned short* whm = ws + WHB_OFF + m * 65536;

  // ---- prologue: stage hidden layers 0 and 1 into the two buffers --------
  #pragma unroll
  for (int b = 0; b < 2; ++b) {
    const char* src = (const char*)(whm + b * 16384);
    char* dst = (char*)wlds[b];
    #pragma unroll
    for (int it = 0; it < 8; ++it) {
      int off = t * 16 + it * 4096;
      gload_lds16(src + off, dst + off);
    }
  }

  uint4  hfrag[2][8];   // h B-frags: [nt][ks], lane holds h[n][16ks+8hi+0..7]
  f32x16 acc[2][4];     // [nt][kt2]

  // ---- layer 1: K=16, exact (no padding) ---------------------------------
  {
    const unsigned short* W1m = ws + W1B_OFF + m * (HDIM * 16);
    const unsigned short* xp  = ws + XB_OFF;
    FRAG w1f[4], xf[2];
    #pragma unroll
    for (int kt2 = 0; kt2 < 4; ++kt2)
      w1f[kt2].v = *(const bf16x8*)&W1m[(kt2 * 32 + l31) * 16 + hi * 8];
    #pragma unroll
    for (int nt = 0; nt < 2; ++nt)
      xf[nt].v = *(const bf16x8*)&xp[(nbw + nt * 32 + l31) * 16 + hi * 8];
    #pragma unroll
    for (int kt2 = 0; kt2 < 4; ++kt2) {
      union { f32x16 v; f32x4 q[4]; } C;
      #pragma unroll
      for (int q = 0; q < 4; ++q)
        C.q[q] = *(const f32x4*)(b1 + m * HDIM + kt2 * 32 + q * 8 + hi * 4);
      #pragma unroll
      for (int nt = 0; nt < 2; ++nt)
        acc[nt][kt2] = MFMA32(w1f[kt2].v, xf[nt].v, C.v);
    }
  }
  build_hfrag(acc, hfrag);

  __syncthreads();   // vmcnt(0) drain: layers 0 & 1 staged and visible

  // ---- 4 hidden layers: W double-buffered, h register-resident -----------
  #pragma unroll
  for (int i = 0; i < 4; ++i) {
    const char* wl = (const char*)wlds[i & 1];
    const float* bp = bh + m * 512 + i * HDIM;

    union { f32x16 v; f32x4 q[4]; } C[4];
    #pragma unroll
    for (int kt2 = 0; kt2 < 4; ++kt2)
      #pragma unroll
      for (int q = 0; q < 4; ++q)
        C[kt2].q[q] = *(const f32x4*)(bp + kt2 * 32 + q * 8 + hi * 4);

    #pragma unroll
    for (int ks = 0; ks < 8; ++ks) {
      FRAG wf[4];
      #pragma unroll
      for (int kt2 = 0; kt2 < 4; ++kt2) {
        int off = (kt2 * 32 + l31) * 256 + ((ks * 32 + hi * 16) ^ ((l31 & 15) << 4));
        wf[kt2].u4 = *(const uint4*)(wl + off);
      }
      #pragma unroll
      for (int kt2 = 0; kt2 < 4; ++kt2)
        #pragma unroll
        for (int nt = 0; nt < 2; ++nt) {
          FRAG hv; hv.u4 = hfrag[nt][ks];
          acc[nt][kt2] = MFMA32(wf[kt2].v, hv.v,
                                ks == 0 ? C[kt2].v : acc[nt][kt2]);
        }
    }
    build_hfrag(acc, hfrag);

    // barrier FIRST: proves all waves finished reading buf[i&1] (and, via
    // the implicit vmcnt(0), that the DMA issued at the end of iter i-1 has
    // landed for everyone). THEN it is safe to overwrite buf[i&1] with the
    // DMA for layer i+2 (consumed at iter i+2, drained by iter i+1's barrier).
    if (i < 3) __syncthreads();
    if (i < 2) {
      const char* src = (const char*)(whm + (i + 2) * 16384);
      char* dst = (char*)wlds[i & 1];
      #pragma unroll
      for (int it = 0; it < 8; ++it) {
        int off = t * 16 + it * 4096;
        gload_lds16(src + off, dst + off);
      }
    }
  }

  // ---- heads: mu (k'=0) and log-sigma (k'=1) ------------------------------
  {
    FRAG hw[8];
    const unsigned short* wp = ws + (l31 == 0 ? WMU_OFF : WSG_OFF) + m * HDIM;
    #pragma unroll
    for (int ks = 0; ks < 8; ++ks) {
      if (l31 < 2) {
        hw[ks].v = *(const bf16x8*)&wp[ks * 16 + hi * 8];
      } else {
        uint4 z; z.x = 0u; z.y = 0u; z.z = 0u; z.w = 0u;
        hw[ks].u4 = z;
      }
    }
    f32x16 C;
    #pragma unroll
    for (int j = 0; j < 16; ++j) C[j] = 0.0f;
    if (hi == 0) { C[0] = bmu[m]; C[1] = bsg[m]; }

    #pragma unroll
    for (int nt = 0; nt < 2; ++nt) {
      f32x16 a2;
      #pragma unroll
      for (int ks = 0; ks < 8; ++ks) {
        FRAG hv; hv.u4 = hfrag[nt][ks];
        a2 = MFMA32(hw[ks].v, hv.v, ks == 0 ? C : a2);
      }
      if (hi == 0) {
        int n = nbw + nt * 32 + l31;
        out[m * NPT + n]          = a2[0];
        out[SG_OFF + m * NPT + n] = expf(a2[1]);
      }
    }
  }
}

extern "C" void kernel_launch(void* const* d_in, const int* in_sizes, int n_in,
                              void* d_out, int out_size, void* d_ws, size_t ws_size,
                              hipStream_t stream) {
  const float* x   = (const float*)d_in[0];
  const float* W1  = (const float*)d_in[1];
  const float* b1  = (const float*)d_in[2];
  const float* Wh  = (const float*)d_in[3];
  const float* bh  = (const float*)d_in[4];
  const float* Wmu = (const float*)d_in[5];
  const float* bmu = (const float*)d_in[6];
  const float* Wsg = (const float*)d_in[7];
  const float* bsg = (const float*)d_in[8];
  unsigned short* ws = (unsigned short*)d_ws;
  (void)in_sizes; (void)n_in; (void)out_size; (void)ws_size;

  cvt_weights<<<(GTOT + 255) / 256, 256, 0, stream>>>(x, W1, Wh, Wmu, Wsg, ws);
  ens_mlp<<<6400, 256, 0, stream>>>(ws, b1, bh, bmu, bsg, (float*)d_out);
}